// Round 11
// baseline (208.418 us; speedup 1.0000x reference)
//
#include <hip/hip_runtime.h>
#include <cstdint>
#include <cstddef>

#define SEQL   2048
#define DMODEL 1024
#define NHEADS 16
#define DHEAD  64
#define MROWS  4096   // BATCH * SEQ

typedef __attribute__((ext_vector_type(8))) short short8;   // 8 bf16 (4 VGPRs)
typedef __attribute__((ext_vector_type(4))) float f32x4;    // MFMA 16x16 C/D
typedef __attribute__((ext_vector_type(4))) unsigned int u32x4;

__device__ __forceinline__ unsigned short f2bf(float x) {
  unsigned int u = __float_as_uint(x);
  u += 0x7fffu + ((u >> 16) & 1u);   // round-to-nearest-even
  return (unsigned short)(u >> 16);
}
__device__ __forceinline__ float bf2f(unsigned short u) {
  return __uint_as_float(((unsigned int)u) << 16);
}
// pack two f32 -> 2xbf16 in one VGPR (RNE, same rounding as f2bf)
__device__ __forceinline__ unsigned int cvtpk(float lo, float hi) {
  unsigned int r;
  asm("v_cvt_pk_bf16_f32 %0, %1, %2" : "=v"(r) : "v"(lo), "v"(hi));
  return r;
}
// load 8 contiguous fp32, round to 8 bf16
__device__ __forceinline__ short8 cvt8(const float* __restrict__ p) {
  const float4 lo = *(const float4*)p;
  const float4 hi = *(const float4*)(p + 4);
  short8 v;
  v[0] = (short)f2bf(lo.x); v[1] = (short)f2bf(lo.y);
  v[2] = (short)f2bf(lo.z); v[3] = (short)f2bf(lo.w);
  v[4] = (short)f2bf(hi.x); v[5] = (short)f2bf(hi.y);
  v[6] = (short)f2bf(hi.z); v[7] = (short)f2bf(hi.w);
  return v;
}
// async global->LDS, 16B per lane; lds base must be wave-uniform
__device__ __forceinline__ void gload_lds16(const unsigned short* g, unsigned short* l) {
  __builtin_amdgcn_global_load_lds(
      (const __attribute__((address_space(1))) unsigned int*)g,
      (__attribute__((address_space(3))) unsigned int*)l, 16, 0, 0);
}

// ---------------------------------------------------------------------------
// One-shot fp32 -> bf16 conversion of x and the four weight matrices,
// PLUS (R21) the RoPE cos/sin table [2048 pos][32 i] float2 (512 KB).
// Table slice (blockIdx.y == 8) replaces the standalone rope kernel's
// transcendental work; identical sincosf/exp2f inputs -> identical rounding.
// ---------------------------------------------------------------------------
__global__ __launch_bounds__(256) void cvt_bf16(
    const float* __restrict__ x,  const float* __restrict__ wq,
    const float* __restrict__ wk, const float* __restrict__ wv,
    const float* __restrict__ wo, const int* __restrict__ pos_arr,
    unsigned short* __restrict__ xb,  unsigned short* __restrict__ wqb,
    unsigned short* __restrict__ wkb, unsigned short* __restrict__ wvb,
    unsigned short* __restrict__ wob, float2* __restrict__ tbl) {
  const int y = blockIdx.y;
  if (y == 8) {
    // RoPE table: id = s*32 + i
    const int id = blockIdx.x * 256 + threadIdx.x;
    if (id < SEQL * 32) {
      const int s = id >> 5, i = id & 31;
      const float pos = (float)pos_arr[s];
      // log2(10000)/32 = 0.4152410118609203
      const float inv = exp2f((float)i * -0.4152410118609203f);
      float ss, cc;
      sincosf(pos * inv, &ss, &cc);
      tbl[id] = make_float2(cc, ss);
    }
    return;
  }
  const float* src; unsigned short* dst;
  if (y < 4)       { src = x + ((size_t)y << 20); dst = xb + ((size_t)y << 20); }
  else if (y == 4) { src = wq; dst = wqb; }
  else if (y == 5) { src = wk; dst = wkb; }
  else if (y == 6) { src = wv; dst = wvb; }
  else             { src = wo; dst = wob; }
  const size_t i = ((size_t)blockIdx.x * 256 + threadIdx.x) * 8;
  *(short8*)(dst + i) = cvt8(src + i);
}

// ---------------------------------------------------------------------------
// QKV projection (m97-style) + R20 bank-conflict swizzle + R21 fused RoPE.
// Epilogue for z=0 (Q, pre-scaled 0.125) and z=1 (K): the rope pair
// (d, d+1) spans adjacent lanes (col = ...+l15), so partner value comes
// from __shfl_xor(.,1); cos/sin from the L2-resident table[pos*32 + d>>1].
// Rotation applied to f32 acc BEFORE the single bf16 rounding (one fewer
// rounding than the old separate rope pass).  z=2 -> V transposed, no rope.
// ---------------------------------------------------------------------------
__global__ __launch_bounds__(256) void gemm_qkv(
    const unsigned short* __restrict__ A,
    const unsigned short* __restrict__ W0, const unsigned short* __restrict__ W1,
    const unsigned short* __restrict__ W2,
    unsigned short* __restrict__ C0, unsigned short* __restrict__ C1,
    unsigned short* __restrict__ Vt, const float2* __restrict__ tbl,
    int Mda, int Nda, int Kda) {
  const unsigned short* W;
  if (blockIdx.z == 0)      W = W0;
  else if (blockIdx.z == 1) W = W1;
  else                      W = W2;

  __shared__ __attribute__((aligned(16))) unsigned short As[128 * 32];
  __shared__ __attribute__((aligned(16))) unsigned short Bs[128 * 32];

  const int t = threadIdx.x;
  const int m0 = blockIdx.y * 128, n0 = blockIdx.x * 128;
  const int w = t >> 6, lane = t & 63;
  const int l15 = lane & 15, quad = lane >> 4;
  const int wm = (w >> 1) * 64, wn = (w & 1) * 64;

  // pre-swizzled source: thread t (physical slot t / 256+t) loads logical
  // slot tx = t ^ ((t>>3)&7)  ->  row = tx>>2, col = (tx&3)*8
  const int tx = t ^ ((t >> 3) & 7);
  const int r1 = tx >> 2,      c1 = (tx & 3) * 8;
  const int r2 = 64 + r1,      c2 = c1;
  unsigned short* asd1 = As + (size_t)(w << 6) * 8;
  unsigned short* asd2 = As + (size_t)(256 + (w << 6)) * 8;
  unsigned short* bsd1 = Bs + (size_t)(w << 6) * 8;
  unsigned short* bsd2 = Bs + (size_t)(256 + (w << 6)) * 8;

  f32x4 acc[4][4] = {};

  for (int k0 = 0; k0 < Kda; k0 += 32) {
    __syncthreads();
    gload_lds16(A + (size_t)(m0 + r1) * Kda + k0 + c1, asd1);
    gload_lds16(A + (size_t)(m0 + r2) * Kda + k0 + c2, asd2);
    gload_lds16(W + (size_t)(n0 + r1) * Kda + k0 + c1, bsd1);
    gload_lds16(W + (size_t)(n0 + r2) * Kda + k0 + c2, bsd2);
    __syncthreads();

    short8 af[4], bfr[4];
#pragma unroll
    for (int i = 0; i < 4; ++i) {
      const int u = (wm + i * 16 + l15) * 4 + quad;
      const int p = u ^ ((u >> 3) & 7);
      af[i] = *(const short8*)(&As[p * 8]);
    }
#pragma unroll
    for (int j = 0; j < 4; ++j) {
      const int u = (wn + j * 16 + l15) * 4 + quad;
      const int p = u ^ ((u >> 3) & 7);
      bfr[j] = *(const short8*)(&Bs[p * 8]);
    }
#pragma unroll
    for (int i = 0; i < 4; ++i)
#pragma unroll
      for (int j = 0; j < 4; ++j)
        acc[i][j] = __builtin_amdgcn_mfma_f32_16x16x32_bf16(af[i], bfr[j], acc[i][j], 0, 0, 0);
  }

  if (blockIdx.z != 2) {
    unsigned short* C = (blockIdx.z == 0) ? C0 : C1;
    const float scale = (blockIdx.z == 0) ? 0.125f : 1.0f;
#pragma unroll
    for (int i = 0; i < 4; ++i)
#pragma unroll
      for (int j = 0; j < 4; ++j) {
        const int col = n0 + wn + j * 16 + l15;
        const int d = col & (DHEAD - 1);
        const int ii = d >> 1;                 // rope pair index
        const bool even = (d & 1) == 0;
#pragma unroll
        for (int r = 0; r < 4; ++r) {
          const int row = m0 + wm + i * 16 + quad * 4 + r;
          const float v = acc[i][j][r];
          const float p = __shfl_xor(v, 1);    // partner lane = col^1
          const float e = even ? v : p;
          const float o = even ? p : v;
          const float2 cssn = tbl[(size_t)(row & (SEQL - 1)) * 32 + ii];
          const float rot = even ? (e * cssn.x - o * cssn.y)
                                 : (e * cssn.y + o * cssn.x);
          C[(size_t)row * Nda + col] = f2bf(rot * scale);
        }
      }
  } else {
    // V transposed write: 4 consecutive s-values per 8B store
#pragma unroll
    for (int i = 0; i < 4; ++i) {
      const int srow = m0 + wm + i * 16 + quad * 4;   // b*SEQL + s (s%4==0)
      const int bq = srow >> 11, s = srow & (SEQL - 1);
#pragma unroll
      for (int j = 0; j < 4; ++j) {
        const int col = n0 + wn + j * 16 + l15;       // h*64 + d
        ushort4 v;
        v.x = f2bf(acc[i][j][0]); v.y = f2bf(acc[i][j][1]);
        v.z = f2bf(acc[i][j][2]); v.w = f2bf(acc[i][j][3]);
        *(ushort4*)(Vt + ((size_t)(bq * DMODEL + col)) * SEQL + s) = v;
      }
    }
  }
}

// ---------------------------------------------------------------------------
// Output projection: A bf16 [M][K], W bf16 [N][K], C fp32 [M][N]
// R20 bank-conflict swizzle kept.
// ---------------------------------------------------------------------------
__global__ __launch_bounds__(256) void gemm_out(
    const unsigned short* __restrict__ A,
    const unsigned short* __restrict__ W,
    float* __restrict__ C,
    int Mda, int Nda, int Kda) {
  __shared__ __attribute__((aligned(16))) unsigned short As[128 * 32];
  __shared__ __attribute__((aligned(16))) unsigned short Bs[128 * 32];

  const int t = threadIdx.x;
  const int m0 = blockIdx.y * 128, n0 = blockIdx.x * 128;
  const int w = t >> 6, lane = t & 63;
  const int l15 = lane & 15, quad = lane >> 4;
  const int wm = (w >> 1) * 64, wn = (w & 1) * 64;

  const int tx = t ^ ((t >> 3) & 7);
  const int r1 = tx >> 2,      c1 = (tx & 3) * 8;
  const int r2 = 64 + r1,      c2 = c1;
  unsigned short* asd1 = As + (size_t)(w << 6) * 8;
  unsigned short* asd2 = As + (size_t)(256 + (w << 6)) * 8;
  unsigned short* bsd1 = Bs + (size_t)(w << 6) * 8;
  unsigned short* bsd2 = Bs + (size_t)(256 + (w << 6)) * 8;

  f32x4 acc[4][4] = {};

  for (int k0 = 0; k0 < Kda; k0 += 32) {
    __syncthreads();
    gload_lds16(A + (size_t)(m0 + r1) * Kda + k0 + c1, asd1);
    gload_lds16(A + (size_t)(m0 + r2) * Kda + k0 + c2, asd2);
    gload_lds16(W + (size_t)(n0 + r1) * Kda + k0 + c1, bsd1);
    gload_lds16(W + (size_t)(n0 + r2) * Kda + k0 + c2, bsd2);
    __syncthreads();

    short8 af[4], bfr[4];
#pragma unroll
    for (int i = 0; i < 4; ++i) {
      const int u = (wm + i * 16 + l15) * 4 + quad;
      const int p = u ^ ((u >> 3) & 7);
      af[i] = *(const short8*)(&As[p * 8]);
    }
#pragma unroll
    for (int j = 0; j < 4; ++j) {
      const int u = (wn + j * 16 + l15) * 4 + quad;
      const int p = u ^ ((u >> 3) & 7);
      bfr[j] = *(const short8*)(&Bs[p * 8]);
    }
#pragma unroll
    for (int i = 0; i < 4; ++i)
#pragma unroll
      for (int j = 0; j < 4; ++j)
        acc[i][j] = __builtin_amdgcn_mfma_f32_16x16x32_bf16(af[i], bfr[j], acc[i][j], 0, 0, 0);
  }

#pragma unroll
  for (int i = 0; i < 4; ++i)
#pragma unroll
    for (int j = 0; j < 4; ++j)
#pragma unroll
      for (int r = 0; r < 4; ++r) {
        int row = m0 + wm + i * 16 + quad * 4 + r;
        int col = n0 + wn + j * 16 + l15;
        C[(size_t)row * Nda + col] = acc[i][j][r];
      }
}

// ---------------------------------------------------------------------------
// Causal attention — R0 structure + R19 serial-chain VALU diet (cvtpk pack +
// lp row-sum in the matrix pipe).
// ---------------------------------------------------------------------------
__global__ __launch_bounds__(256, 2) void attn_kernel(const unsigned short* __restrict__ Kf,
                                                      const unsigned short* __restrict__ Vt,
                                                      unsigned short* __restrict__ Qio) {
  __shared__ __attribute__((aligned(16))) unsigned short Ks[4096];  // 8 KB: kv64 x d64
  __shared__ __attribute__((aligned(16))) unsigned short Vs[4096];  // 8 KB: d64 x kv64

  const int id = blockIdx.x;                    // id = grp*128 + qpair*8 + xcd
  const int bh = ((id >> 7) << 3) | (id & 7);   // grp*8 + xcd (L2 locality)
  const int qpair = (id >> 3) & 15;             // 0..15
  const int b = bh >> 4, h = bh & 15;
  const int w = threadIdx.x >> 6;
  const int lane = threadIdx.x & 63;
  const int l15 = lane & 15, quad = lane >> 4;

  // staging source addresses (lane-permuted so LDS slot = fragment layout)
  const int g = (w << 6) | lane;
  const int ktau = g >> 7, kseg = (g >> 4) & 7, km = g & 15;
  const int kvl = 8 * (km >> 2) + (km & 3) + 4 * ktau;
  const unsigned short* kstage = Kf + ((size_t)(b * SEQL + kvl)) * DMODEL + h * DHEAD + kseg * 8;
  const int vdb = (g >> 6) & 3, vq = (g >> 4) & 3, vm = g & 15;
  const unsigned short* vstage = Vt + ((size_t)(bh * DHEAD + vdb * 16 + vm)) * SEQL + vq * 8;
  unsigned short* kdst0 = Ks + (size_t)(w << 6) * 8;          // kv 0..31 half
  unsigned short* kdst1 = Ks + 2048 + (size_t)(w << 6) * 8;   // kv 32..63 half
  unsigned short* vdst0 = Vs + (size_t)(w << 6) * 8;
  unsigned short* vdst1 = Vs + 2048 + (size_t)(w << 6) * 8;

  // fragment read offset (shorts) within a 2048-short half
  const int rs = (l15 + (quad << 4)) << 3;

  // all-ones bf16 A-fragment for the lp row-sum MFMA
  const short8 ones = {(short)0x3F80, (short)0x3F80, (short)0x3F80, (short)0x3F80,
                       (short)0x3F80, (short)0x3F80, (short)0x3F80, (short)0x3F80};

#pragma unroll 1
  for (int phase = 0; phase < 2; ++phase) {
    const int qblk = (phase == 0) ? qpair : 31 - qpair;
    const int qw = qblk * 64 + w * 16;
    const int qrow = qw + l15;

    // Q B-frag: n=l15 (q), k=8*quad+j (d)
    const unsigned short* qp = Qio + ((size_t)(b * SEQL + qrow)) * DMODEL + h * DHEAD + quad * 8;
    const short8 bq0 = *(const short8*)(qp);
    const short8 bq1 = *(const short8*)(qp + 32);

    f32x4 oa0 = {0.f, 0.f, 0.f, 0.f}, oa1 = oa0, oa2 = oa0, oa3 = oa0;
    f32x4 lpacc = oa0;

    const int trips = qblk + 1;   // kv64 tiles; block-uniform
    for (int t = 0; t < trips; ++t) {
      const int kv0 = t * 64;
      __syncthreads();   // all waves done reading previous tile
      gload_lds16(kstage + (size_t)kv0 * DMODEL, kdst0);
      gload_lds16(kstage + (size_t)(kv0 + 32) * DMODEL, kdst1);
      gload_lds16(vstage + kv0, vdst0);
      gload_lds16(vstage + kv0 + 32, vdst1);
      __syncthreads();   // staged data visible

      // QK^T: 4 score accumulators (kv groups +0, +4, +32, +36)
      const short8 ak10 = *(const short8*)(Ks + rs);
      const short8 ak11 = *(const short8*)(Ks + rs + 512);
      const short8 ak20 = *(const short8*)(Ks + rs + 1024);
      const short8 ak21 = *(const short8*)(Ks + rs + 1536);
      const short8 ak30 = *(const short8*)(Ks + 2048 + rs);
      const short8 ak31 = *(const short8*)(Ks + 2048 + rs + 512);
      const short8 ak40 = *(const short8*)(Ks + 2048 + rs + 1024);
      const short8 ak41 = *(const short8*)(Ks + 2048 + rs + 1536);
      f32x4 z = {0.f, 0.f, 0.f, 0.f};
      f32x4 s1 = __builtin_amdgcn_mfma_f32_16x16x32_bf16(ak10, bq0, z, 0, 0, 0);
      s1 = __builtin_amdgcn_mfma_f32_16x16x32_bf16(ak11, bq1, s1, 0, 0, 0);
      f32x4 s2 = __builtin_amdgcn_mfma_f32_16x16x32_bf16(ak20, bq0, z, 0, 0, 0);
      s2 = __builtin_amdgcn_mfma_f32_16x16x32_bf16(ak21, bq1, s2, 0, 0, 0);
      f32x4 s3 = __builtin_amdgcn_mfma_f32_16x16x32_bf16(ak30, bq0, z, 0, 0, 0);
      s3 = __builtin_amdgcn_mfma_f32_16x16x32_bf16(ak31, bq1, s3, 0, 0, 0);
      f32x4 s4 = __builtin_amdgcn_mfma_f32_16x16x32_bf16(ak40, bq0, z, 0, 0, 0);
      s4 = __builtin_amdgcn_mfma_f32_16x16x32_bf16(ak41, bq1, s4, 0, 0, 0);

      // exp (+causal mask on the straddle trip) -> PV B-operands via cvtpk
      short8 bp0, bp1;
      if (kv0 + 63 <= qw) {   // wave-uniform fast path: no masking needed
        const float p10 = __expf(s1[0]), p11 = __expf(s1[1]);
        const float p12 = __expf(s1[2]), p13 = __expf(s1[3]);
        const float p20 = __expf(s2[0]), p21 = __expf(s2[1]);
        const float p22 = __expf(s2[2]), p23 = __expf(s2[3]);
        const float p30 = __expf(s3[0]), p31 = __expf(s3[1]);
        const float p32 = __expf(s3[2]), p33 = __expf(s3[3]);
        const float p40 = __expf(s4[0]), p41 = __expf(s4[1]);
        const float p42 = __expf(s4[2]), p43 = __expf(s4[3]);
        u32x4 lo, hi;
        lo[0] = cvtpk(p10, p11); lo[1] = cvtpk(p12, p13);
        lo[2] = cvtpk(p20, p21); lo[3] = cvtpk(p22, p23);
        hi[0] = cvtpk(p30, p31); hi[1] = cvtpk(p32, p33);
        hi[2] = cvtpk(p40, p41); hi[3] = cvtpk(p42, p43);
        bp0 = __builtin_bit_cast(short8, lo);
        bp1 = __builtin_bit_cast(short8, hi);
      } else {
        float p1[4], p2[4], p3[4], p4[4];
#pragma unroll
        for (int r = 0; r < 4; ++r) {
          const int kv1 = kv0 + 8 * quad + r;
          p1[r] = (kv1 > qrow)      ? 0.f : __expf(s1[r]);
          p2[r] = (kv1 + 4 > qrow)  ? 0.f : __expf(s2[r]);
          p3[r] = (kv1 + 32 > qrow) ? 0.f : __expf(s3[r]);
          p4[r] = (kv1 + 36 > qrow) ? 0.f : __expf(s4[r]);
        }
        u32x4 lo, hi;
        lo[0] = cvtpk(p1[0], p1[1]); lo[1] = cvtpk(p1[2], p1[3]);
        lo[2] = cvtpk(p2[0], p2[1]); lo[3] = cvtpk(p2[2], p2[3]);
        hi[0] = cvtpk(p3[0], p3[1]); hi[1] = cvtpk(p3[2], p3[3]);
        hi[2] = cvtpk(p4[0], p4[1]); hi[3] = cvtpk(p4[2], p4[3]);
        bp0 = __builtin_bit_cast(short8, lo);
        bp1 = __builtin_bit_cast(short8, hi);
      }

      // lp row-sum in the matrix pipe: D[row,q] = sum_k 1 * P[k,q]
      lpacc = __builtin_amdgcn_mfma_f32_16x16x32_bf16(ones, bp0, lpacc, 0, 0, 0);
      lpacc = __builtin_amdgcn_mfma_f32_16x16x32_bf16(ones, bp1, lpacc, 0, 0, 0);

      // PV: A = V^T frags (d-block x kv-half), B = bp
      const short8 av0l = *(const short8*)(Vs + rs);
      const short8 av1l = *(const short8*)(Vs + rs + 512);
      const short8 av2l = *(const short8*)(Vs + rs + 1024);
      const short8 av3l = *(const short8*)(Vs + rs + 1536);
      const short8 av0h = *(const short8*)(Vs + 2048 + rs);
      const short8 av1h = *(const short8*)(Vs + 2048 + rs + 512);
      const short8 av2h = *(const short8*)(Vs + 2048 + rs + 1024);
      const short8 av3h = *(const short8*)(Vs + 2048 + rs + 1536);
      oa0 = __builtin_amdgcn_mfma_f32_16x16x32_bf16(av0l, bp0, oa0, 0, 0, 0);
      oa1 = __builtin_amdgcn_mfma_f32_16x16x32_bf16(av1l, bp0, oa1, 0, 0, 0);
      oa2 = __builtin_amdgcn_mfma_f32_16x16x32_bf16(av2l, bp0, oa2, 0, 0, 0);
      oa3 = __builtin_amdgcn_mfma_f32_16x16x32_bf16(av3l, bp0, oa3, 0, 0, 0);
      oa0 = __builtin_amdgcn_mfma_f32_16x16x32_bf16(av0h, bp1, oa0, 0, 0, 0);
      oa1 = __builtin_amdgcn_mfma_f32_16x16x32_bf16(av1h, bp1, oa1, 0, 0, 0);
      oa2 = __builtin_amdgcn_mfma_f32_16x16x32_bf16(av2h, bp1, oa2, 0, 0, 0);
      oa3 = __builtin_amdgcn_mfma_f32_16x16x32_bf16(av3h, bp1, oa3, 0, 0, 0);
    }

    // lpacc[0] holds sum_kv P[q=l15] (all rows identical; k-reduction done
    // inside the MFMA, so no cross-quad shuffle needed)
    const float il = 1.f / lpacc[0];

    // O^T: lane holds q=l15's d = db*16 + 4*quad + r  -> 4x ushort4 stores
    unsigned short* ob = Qio + ((size_t)(b * SEQL + qrow)) * DMODEL + h * DHEAD + quad * 4;
    {
      ushort4 v;
      v.x = f2bf(oa0[0] * il); v.y = f2bf(oa0[1] * il);
      v.z = f2bf(oa0[2] * il); v.w = f2bf(oa0[3] * il);
      *(ushort4*)(ob) = v;
      v.x = f2bf(oa1[0] * il); v.y = f2bf(oa1[1] * il);
      v.z = f2bf(oa1[2] * il); v.w = f2bf(oa1[3] * il);
      *(ushort4*)(ob + 16) = v;
      v.x = f2bf(oa2[0] * il); v.y = f2bf(oa2[1] * il);
      v.z = f2bf(oa2[2] * il); v.w = f2bf(oa2[3] * il);
      *(ushort4*)(ob + 32) = v;
      v.x = f2bf(oa3[0] * il); v.y = f2bf(oa3[1] * il);
      v.z = f2bf(oa3[2] * il); v.w = f2bf(oa3[3] * il);
      *(ushort4*)(ob + 48) = v;
    }
  }
}

// ---------------------------------------------------------------------------
extern "C" void kernel_launch(void* const* d_in, const int* in_sizes, int n_in,
                              void* d_out, int out_size, void* d_ws, size_t ws_size,
                              hipStream_t stream) {
  (void)in_sizes; (void)n_in; (void)out_size; (void)ws_size;
  const float* x  = (const float*)d_in[0];
  const int* tpos = (const int*)d_in[1];
  const float* Wq = (const float*)d_in[2];
  const float* Wk = (const float*)d_in[3];
  const float* Wv = (const float*)d_in[4];
  const float* Wo = (const float*)d_in[5];
  float* out      = (float*)d_out;

  char* ws = (char*)d_ws;
  const size_t MB = 1024 * 1024;
  unsigned short* Qf  = (unsigned short*)(ws);            // 8 MB
  unsigned short* Kf  = (unsigned short*)(ws + 8 * MB);   // 8 MB
  unsigned short* Vt  = (unsigned short*)(ws + 16 * MB);  // 8 MB
  unsigned short* xb  = (unsigned short*)(ws + 24 * MB);  // 8 MB
  unsigned short* wqb = (unsigned short*)(ws + 32 * MB);  // 2 MB
  unsigned short* wkb = (unsigned short*)(ws + 34 * MB);  // 2 MB
  unsigned short* wvb = (unsigned short*)(ws + 36 * MB);  // 2 MB
  unsigned short* wob = (unsigned short*)(ws + 38 * MB);  // 2 MB
  float2* tbl         = (float2*)(ws + 40 * MB);          // 512 KB -> 40.5 MB

  // fp32 -> bf16 conversion (x + 4 weights) + RoPE cos/sin table (y==8)
  cvt_bf16<<<dim3(512, 9), 256, 0, stream>>>(x, Wq, Wk, Wv, Wo, tpos,
                                             xb, wqb, wkb, wvb, wob, tbl);
  // Q,K,V projections with FUSED RoPE on Q (pre-scaled 0.125) and K;
  // V written transposed.  (rope_inplace kernel deleted: -1 launch.)
  gemm_qkv<<<dim3(8, 32, 3), 256, 0, stream>>>(xb, wqb, wkb, wvb, Qf, Kf, Vt,
                                               tbl, MROWS, DMODEL, DMODEL);
  // causal attention; 512 paired blocks (uniform 33 trips), XCD-swizzled
  attn_kernel<<<dim3(512), 256, 0, stream>>>(Kf, Vt, Qf);
  // output projection (bf16 A, bf16 W, fp32 out)
  gemm_out<<<dim3(8, 32, 1), 256, 0, stream>>>(Qf, wob, out, MROWS, DMODEL, DMODEL);
}

// Round 13
// 191.364 us; speedup vs baseline: 1.0891x; 1.0891x over previous
//
#include <hip/hip_runtime.h>
#include <cstdint>
#include <cstddef>

#define SEQL   2048
#define DMODEL 1024
#define NHEADS 16
#define DHEAD  64
#define MROWS  4096   // BATCH * SEQ

typedef __attribute__((ext_vector_type(8))) short short8;   // 8 bf16 (4 VGPRs)
typedef __attribute__((ext_vector_type(4))) float f32x4;    // MFMA 16x16 C/D
typedef __attribute__((ext_vector_type(4))) unsigned int u32x4;

__device__ __forceinline__ unsigned short f2bf(float x) {
  unsigned int u = __float_as_uint(x);
  u += 0x7fffu + ((u >> 16) & 1u);   // round-to-nearest-even
  return (unsigned short)(u >> 16);
}
__device__ __forceinline__ float bf2f(unsigned short u) {
  return __uint_as_float(((unsigned int)u) << 16);
}
// pack two f32 -> 2xbf16 in one VGPR (RNE, same rounding as f2bf)
__device__ __forceinline__ unsigned int cvtpk(float lo, float hi) {
  unsigned int r;
  asm("v_cvt_pk_bf16_f32 %0, %1, %2" : "=v"(r) : "v"(lo), "v"(hi));
  return r;
}
// load 8 contiguous fp32, round to 8 bf16
__device__ __forceinline__ short8 cvt8(const float* __restrict__ p) {
  const float4 lo = *(const float4*)p;
  const float4 hi = *(const float4*)(p + 4);
  short8 v;
  v[0] = (short)f2bf(lo.x); v[1] = (short)f2bf(lo.y);
  v[2] = (short)f2bf(lo.z); v[3] = (short)f2bf(lo.w);
  v[4] = (short)f2bf(hi.x); v[5] = (short)f2bf(hi.y);
  v[6] = (short)f2bf(hi.z); v[7] = (short)f2bf(hi.w);
  return v;
}
// async global->LDS, 16B per lane; lds base must be wave-uniform,
// GLOBAL SOURCE IS PER-LANE (lane l's 16B land at lds_base + l*16).
__device__ __forceinline__ void gload_lds16(const unsigned short* g, unsigned short* l) {
  __builtin_amdgcn_global_load_lds(
      (const __attribute__((address_space(1))) unsigned int*)g,
      (__attribute__((address_space(3))) unsigned int*)l, 16, 0, 0);
}

// ---------------------------------------------------------------------------
// One-shot fp32 -> bf16 conversion of x and the four weight matrices,
// PLUS the RoPE cos/sin table [2048 pos][32 i] float2 (512 KB, y==8 slice).
// ---------------------------------------------------------------------------
__global__ __launch_bounds__(256) void cvt_bf16(
    const float* __restrict__ x,  const float* __restrict__ wq,
    const float* __restrict__ wk, const float* __restrict__ wv,
    const float* __restrict__ wo, const int* __restrict__ pos_arr,
    unsigned short* __restrict__ xb,  unsigned short* __restrict__ wqb,
    unsigned short* __restrict__ wkb, unsigned short* __restrict__ wvb,
    unsigned short* __restrict__ wob, float2* __restrict__ tbl) {
  const int y = blockIdx.y;
  if (y == 8) {
    // RoPE table: id = s*32 + i
    const int id = blockIdx.x * 256 + threadIdx.x;
    if (id < SEQL * 32) {
      const int s = id >> 5, i = id & 31;
      const float pos = (float)pos_arr[s];
      // log2(10000)/32 = 0.4152410118609203
      const float inv = exp2f((float)i * -0.4152410118609203f);
      float ss, cc;
      sincosf(pos * inv, &ss, &cc);
      tbl[id] = make_float2(cc, ss);
    }
    return;
  }
  const float* src; unsigned short* dst;
  if (y < 4)       { src = x + ((size_t)y << 20); dst = xb + ((size_t)y << 20); }
  else if (y == 4) { src = wq; dst = wqb; }
  else if (y == 5) { src = wk; dst = wkb; }
  else if (y == 6) { src = wv; dst = wvb; }
  else             { src = wo; dst = wob; }
  const size_t i = ((size_t)blockIdx.x * 256 + threadIdx.x) * 8;
  *(short8*)(dst + i) = cvt8(src + i);
}

// ---------------------------------------------------------------------------
// QKV projection (m97-style) + R20 bank-conflict swizzle + R23 fused RoPE.
// R22 post-mortem: table staging passed a WAVE-UNIFORM global address to
// gload_lds16 (source must be per-lane!) -> each 1KB segment was one float2
// replicated 64x -> absmax 2.38.  Fix: + lane*8 shorts (16B/lane) on the
// source.  Everything else identical to R22 (R21 proved the fused math).
// z=0 -> Q (pre-scaled 0.125); z=1 -> K; z=2 -> V transposed, no rope.
// ---------------------------------------------------------------------------
__global__ __launch_bounds__(256) void gemm_qkv(
    const unsigned short* __restrict__ A,
    const unsigned short* __restrict__ W0, const unsigned short* __restrict__ W1,
    const unsigned short* __restrict__ W2,
    unsigned short* __restrict__ C0, unsigned short* __restrict__ C1,
    unsigned short* __restrict__ Vt, const float2* __restrict__ tbl,
    int Mda, int Nda, int Kda) {
  const unsigned short* W;
  if (blockIdx.z == 0)      W = W0;
  else if (blockIdx.z == 1) W = W1;
  else                      W = W2;

  __shared__ __attribute__((aligned(16))) unsigned short As[128 * 32];
  __shared__ __attribute__((aligned(16))) unsigned short Bs[128 * 32];
  __shared__ __attribute__((aligned(16))) float2 Ts[128 * 32];   // 32 KB

  const int t = threadIdx.x;
  const int m0 = blockIdx.y * 128, n0 = blockIdx.x * 128;
  const int w = t >> 6, lane = t & 63;
  const int l15 = lane & 15, quad = lane >> 4;
  const int wm = (w >> 1) * 64, wn = (w & 1) * 64;

  // pre-swizzled source: thread t (physical slot t / 256+t) loads logical
  // slot tx = t ^ ((t>>3)&7)  ->  row = tx>>2, col = (tx&3)*8
  const int tx = t ^ ((t >> 3) & 7);
  const int r1 = tx >> 2,      c1 = (tx & 3) * 8;
  const int r2 = 64 + r1,      c2 = c1;
  unsigned short* asd1 = As + (size_t)(w << 6) * 8;
  unsigned short* asd2 = As + (size_t)(256 + (w << 6)) * 8;
  unsigned short* bsd1 = Bs + (size_t)(w << 6) * 8;
  unsigned short* bsd2 = Bs + (size_t)(256 + (w << 6)) * 8;

  // stage this block's RoPE table slice (rows s0..s0+127, contiguous 32 KB)
  // into Ts; PER-LANE source offset (lane*16B) matches the hardware's
  // lane*16B LDS placement -> linear copy.  First K-loop __syncthreads
  // (vmcnt(0) drain) makes it visible long before the epilogue reads it.
  if (blockIdx.z != 2) {
    const int s0 = m0 & (SEQL - 1);
    const unsigned short* tsrc = (const unsigned short*)(tbl + (size_t)s0 * 32);
    unsigned short* tdst = (unsigned short*)Ts;
#pragma unroll
    for (int c = 0; c < 8; ++c) {
      const size_t seg = (size_t)(c * 4 + w) * 512;   // shorts (1 KB per wave-seg)
      gload_lds16(tsrc + seg + (size_t)lane * 8, tdst + seg);
    }
  }

  f32x4 acc[4][4] = {};

  for (int k0 = 0; k0 < Kda; k0 += 32) {
    __syncthreads();
    gload_lds16(A + (size_t)(m0 + r1) * Kda + k0 + c1, asd1);
    gload_lds16(A + (size_t)(m0 + r2) * Kda + k0 + c2, asd2);
    gload_lds16(W + (size_t)(n0 + r1) * Kda + k0 + c1, bsd1);
    gload_lds16(W + (size_t)(n0 + r2) * Kda + k0 + c2, bsd2);
    __syncthreads();

    short8 af[4], bfr[4];
#pragma unroll
    for (int i = 0; i < 4; ++i) {
      const int u = (wm + i * 16 + l15) * 4 + quad;
      const int p = u ^ ((u >> 3) & 7);
      af[i] = *(const short8*)(&As[p * 8]);
    }
#pragma unroll
    for (int j = 0; j < 4; ++j) {
      const int u = (wn + j * 16 + l15) * 4 + quad;
      const int p = u ^ ((u >> 3) & 7);
      bfr[j] = *(const short8*)(&Bs[p * 8]);
    }
#pragma unroll
    for (int i = 0; i < 4; ++i)
#pragma unroll
      for (int j = 0; j < 4; ++j)
        acc[i][j] = __builtin_amdgcn_mfma_f32_16x16x32_bf16(af[i], bfr[j], acc[i][j], 0, 0, 0);
  }

  if (blockIdx.z != 2) {
    unsigned short* C = (blockIdx.z == 0) ? C0 : C1;
    const float scale = (blockIdx.z == 0) ? 0.125f : 1.0f;
    const int ii_base = (l15 >> 1);              // + j*8
    const bool even = (l15 & 1) == 0;
#pragma unroll
    for (int i = 0; i < 4; ++i)
#pragma unroll
      for (int j = 0; j < 4; ++j) {
        const int col = n0 + wn + j * 16 + l15;
        const int ii = j * 8 + ii_base;          // rope pair index (d>>1)
#pragma unroll
        for (int r = 0; r < 4; ++r) {
          const int lrow = wm + i * 16 + quad * 4 + r;
          const float v = acc[i][j][r];
          const float p = __shfl_xor(v, 1);      // partner lane = col^1
          const float e = even ? v : p;
          const float o = even ? p : v;
          const float2 cssn = Ts[lrow * 32 + ii];
          const float rot = even ? (e * cssn.x - o * cssn.y)
                                 : (e * cssn.y + o * cssn.x);
          C[(size_t)(m0 + lrow) * Nda + col] = f2bf(rot * scale);
        }
      }
  } else {
    // V transposed write: 4 consecutive s-values per 8B store
#pragma unroll
    for (int i = 0; i < 4; ++i) {
      const int srow = m0 + wm + i * 16 + quad * 4;   // b*SEQL + s (s%4==0)
      const int bq = srow >> 11, s = srow & (SEQL - 1);
#pragma unroll
      for (int j = 0; j < 4; ++j) {
        const int col = n0 + wn + j * 16 + l15;       // h*64 + d
        ushort4 v;
        v.x = f2bf(acc[i][j][0]); v.y = f2bf(acc[i][j][1]);
        v.z = f2bf(acc[i][j][2]); v.w = f2bf(acc[i][j][3]);
        *(ushort4*)(Vt + ((size_t)(bq * DMODEL + col)) * SEQL + s) = v;
      }
    }
  }
}

// ---------------------------------------------------------------------------
// Output projection: A bf16 [M][K], W bf16 [N][K], C fp32 [M][N]
// R20 bank-conflict swizzle kept.
// ---------------------------------------------------------------------------
__global__ __launch_bounds__(256) void gemm_out(
    const unsigned short* __restrict__ A,
    const unsigned short* __restrict__ W,
    float* __restrict__ C,
    int Mda, int Nda, int Kda) {
  __shared__ __attribute__((aligned(16))) unsigned short As[128 * 32];
  __shared__ __attribute__((aligned(16))) unsigned short Bs[128 * 32];

  const int t = threadIdx.x;
  const int m0 = blockIdx.y * 128, n0 = blockIdx.x * 128;
  const int w = t >> 6, lane = t & 63;
  const int l15 = lane & 15, quad = lane >> 4;
  const int wm = (w >> 1) * 64, wn = (w & 1) * 64;

  const int tx = t ^ ((t >> 3) & 7);
  const int r1 = tx >> 2,      c1 = (tx & 3) * 8;
  const int r2 = 64 + r1,      c2 = c1;
  unsigned short* asd1 = As + (size_t)(w << 6) * 8;
  unsigned short* asd2 = As + (size_t)(256 + (w << 6)) * 8;
  unsigned short* bsd1 = Bs + (size_t)(w << 6) * 8;
  unsigned short* bsd2 = Bs + (size_t)(256 + (w << 6)) * 8;

  f32x4 acc[4][4] = {};

  for (int k0 = 0; k0 < Kda; k0 += 32) {
    __syncthreads();
    gload_lds16(A + (size_t)(m0 + r1) * Kda + k0 + c1, asd1);
    gload_lds16(A + (size_t)(m0 + r2) * Kda + k0 + c2, asd2);
    gload_lds16(W + (size_t)(n0 + r1) * Kda + k0 + c1, bsd1);
    gload_lds16(W + (size_t)(n0 + r2) * Kda + k0 + c2, bsd2);
    __syncthreads();

    short8 af[4], bfr[4];
#pragma unroll
    for (int i = 0; i < 4; ++i) {
      const int u = (wm + i * 16 + l15) * 4 + quad;
      const int p = u ^ ((u >> 3) & 7);
      af[i] = *(const short8*)(&As[p * 8]);
    }
#pragma unroll
    for (int j = 0; j < 4; ++j) {
      const int u = (wn + j * 16 + l15) * 4 + quad;
      const int p = u ^ ((u >> 3) & 7);
      bfr[j] = *(const short8*)(&Bs[p * 8]);
    }
#pragma unroll
    for (int i = 0; i < 4; ++i)
#pragma unroll
      for (int j = 0; j < 4; ++j)
        acc[i][j] = __builtin_amdgcn_mfma_f32_16x16x32_bf16(af[i], bfr[j], acc[i][j], 0, 0, 0);
  }

#pragma unroll
  for (int i = 0; i < 4; ++i)
#pragma unroll
    for (int j = 0; j < 4; ++j)
#pragma unroll
      for (int r = 0; r < 4; ++r) {
        int row = m0 + wm + i * 16 + quad * 4 + r;
        int col = n0 + wn + j * 16 + l15;
        C[(size_t)row * Nda + col] = acc[i][j][r];
      }
}

// ---------------------------------------------------------------------------
// Causal attention — R0 structure + R19 serial-chain VALU diet (cvtpk pack +
// lp row-sum in the matrix pipe).
// ---------------------------------------------------------------------------
__global__ __launch_bounds__(256, 2) void attn_kernel(const unsigned short* __restrict__ Kf,
                                                      const unsigned short* __restrict__ Vt,
                                                      unsigned short* __restrict__ Qio) {
  __shared__ __attribute__((aligned(16))) unsigned short Ks[4096];  // 8 KB: kv64 x d64
  __shared__ __attribute__((aligned(16))) unsigned short Vs[4096];  // 8 KB: d64 x kv64

  const int id = blockIdx.x;                    // id = grp*128 + qpair*8 + xcd
  const int bh = ((id >> 7) << 3) | (id & 7);   // grp*8 + xcd (L2 locality)
  const int qpair = (id >> 3) & 15;             // 0..15
  const int b = bh >> 4, h = bh & 15;
  const int w = threadIdx.x >> 6;
  const int lane = threadIdx.x & 63;
  const int l15 = lane & 15, quad = lane >> 4;

  // staging source addresses (lane-permuted so LDS slot = fragment layout)
  const int g = (w << 6) | lane;
  const int ktau = g >> 7, kseg = (g >> 4) & 7, km = g & 15;
  const int kvl = 8 * (km >> 2) + (km & 3) + 4 * ktau;
  const unsigned short* kstage = Kf + ((size_t)(b * SEQL + kvl)) * DMODEL + h * DHEAD + kseg * 8;
  const int vdb = (g >> 6) & 3, vq = (g >> 4) & 3, vm = g & 15;
  const unsigned short* vstage = Vt + ((size_t)(bh * DHEAD + vdb * 16 + vm)) * SEQL + vq * 8;
  unsigned short* kdst0 = Ks + (size_t)(w << 6) * 8;          // kv 0..31 half
  unsigned short* kdst1 = Ks + 2048 + (size_t)(w << 6) * 8;   // kv 32..63 half
  unsigned short* vdst0 = Vs + (size_t)(w << 6) * 8;
  unsigned short* vdst1 = Vs + 2048 + (size_t)(w << 6) * 8;

  // fragment read offset (shorts) within a 2048-short half
  const int rs = (l15 + (quad << 4)) << 3;

  // all-ones bf16 A-fragment for the lp row-sum MFMA
  const short8 ones = {(short)0x3F80, (short)0x3F80, (short)0x3F80, (short)0x3F80,
                       (short)0x3F80, (short)0x3F80, (short)0x3F80, (short)0x3F80};

#pragma unroll 1
  for (int phase = 0; phase < 2; ++phase) {
    const int qblk = (phase == 0) ? qpair : 31 - qpair;
    const int qw = qblk * 64 + w * 16;
    const int qrow = qw + l15;

    // Q B-frag: n=l15 (q), k=8*quad+j (d)
    const unsigned short* qp = Qio + ((size_t)(b * SEQL + qrow)) * DMODEL + h * DHEAD + quad * 8;
    const short8 bq0 = *(const short8*)(qp);
    const short8 bq1 = *(const short8*)(qp + 32);

    f32x4 oa0 = {0.f, 0.f, 0.f, 0.f}, oa1 = oa0, oa2 = oa0, oa3 = oa0;
    f32x4 lpacc = oa0;

    const int trips = qblk + 1;   // kv64 tiles; block-uniform
    for (int t = 0; t < trips; ++t) {
      const int kv0 = t * 64;
      __syncthreads();   // all waves done reading previous tile
      gload_lds16(kstage + (size_t)kv0 * DMODEL, kdst0);
      gload_lds16(kstage + (size_t)(kv0 + 32) * DMODEL, kdst1);
      gload_lds16(vstage + kv0, vdst0);
      gload_lds16(vstage + kv0 + 32, vdst1);
      __syncthreads();   // staged data visible

      // QK^T: 4 score accumulators (kv groups +0, +4, +32, +36)
      const short8 ak10 = *(const short8*)(Ks + rs);
      const short8 ak11 = *(const short8*)(Ks + rs + 512);
      const short8 ak20 = *(const short8*)(Ks + rs + 1024);
      const short8 ak21 = *(const short8*)(Ks + rs + 1536);
      const short8 ak30 = *(const short8*)(Ks + 2048 + rs);
      const short8 ak31 = *(const short8*)(Ks + 2048 + rs + 512);
      const short8 ak40 = *(const short8*)(Ks + 2048 + rs + 1024);
      const short8 ak41 = *(const short8*)(Ks + 2048 + rs + 1536);
      f32x4 z = {0.f, 0.f, 0.f, 0.f};
      f32x4 s1 = __builtin_amdgcn_mfma_f32_16x16x32_bf16(ak10, bq0, z, 0, 0, 0);
      s1 = __builtin_amdgcn_mfma_f32_16x16x32_bf16(ak11, bq1, s1, 0, 0, 0);
      f32x4 s2 = __builtin_amdgcn_mfma_f32_16x16x32_bf16(ak20, bq0, z, 0, 0, 0);
      s2 = __builtin_amdgcn_mfma_f32_16x16x32_bf16(ak21, bq1, s2, 0, 0, 0);
      f32x4 s3 = __builtin_amdgcn_mfma_f32_16x16x32_bf16(ak30, bq0, z, 0, 0, 0);
      s3 = __builtin_amdgcn_mfma_f32_16x16x32_bf16(ak31, bq1, s3, 0, 0, 0);
      f32x4 s4 = __builtin_amdgcn_mfma_f32_16x16x32_bf16(ak40, bq0, z, 0, 0, 0);
      s4 = __builtin_amdgcn_mfma_f32_16x16x32_bf16(ak41, bq1, s4, 0, 0, 0);

      // exp (+causal mask on the straddle trip) -> PV B-operands via cvtpk
      short8 bp0, bp1;
      if (kv0 + 63 <= qw) {   // wave-uniform fast path: no masking needed
        const float p10 = __expf(s1[0]), p11 = __expf(s1[1]);
        const float p12 = __expf(s1[2]), p13 = __expf(s1[3]);
        const float p20 = __expf(s2[0]), p21 = __expf(s2[1]);
        const float p22 = __expf(s2[2]), p23 = __expf(s2[3]);
        const float p30 = __expf(s3[0]), p31 = __expf(s3[1]);
        const float p32 = __expf(s3[2]), p33 = __expf(s3[3]);
        const float p40 = __expf(s4[0]), p41 = __expf(s4[1]);
        const float p42 = __expf(s4[2]), p43 = __expf(s4[3]);
        u32x4 lo, hi;
        lo[0] = cvtpk(p10, p11); lo[1] = cvtpk(p12, p13);
        lo[2] = cvtpk(p20, p21); lo[3] = cvtpk(p22, p23);
        hi[0] = cvtpk(p30, p31); hi[1] = cvtpk(p32, p33);
        hi[2] = cvtpk(p40, p41); hi[3] = cvtpk(p42, p43);
        bp0 = __builtin_bit_cast(short8, lo);
        bp1 = __builtin_bit_cast(short8, hi);
      } else {
        float p1[4], p2[4], p3[4], p4[4];
#pragma unroll
        for (int r = 0; r < 4; ++r) {
          const int kv1 = kv0 + 8 * quad + r;
          p1[r] = (kv1 > qrow)      ? 0.f : __expf(s1[r]);
          p2[r] = (kv1 + 4 > qrow)  ? 0.f : __expf(s2[r]);
          p3[r] = (kv1 + 32 > qrow) ? 0.f : __expf(s3[r]);
          p4[r] = (kv1 + 36 > qrow) ? 0.f : __expf(s4[r]);
        }
        u32x4 lo, hi;
        lo[0] = cvtpk(p1[0], p1[1]); lo[1] = cvtpk(p1[2], p1[3]);
        lo[2] = cvtpk(p2[0], p2[1]); lo[3] = cvtpk(p2[2], p2[3]);
        hi[0] = cvtpk(p3[0], p3[1]); hi[1] = cvtpk(p3[2], p3[3]);
        hi[2] = cvtpk(p4[0], p4[1]); hi[3] = cvtpk(p4[2], p4[3]);
        bp0 = __builtin_bit_cast(short8, lo);
        bp1 = __builtin_bit_cast(short8, hi);
      }

      // lp row-sum in the matrix pipe: D[row,q] = sum_k 1 * P[k,q]
      lpacc = __builtin_amdgcn_mfma_f32_16x16x32_bf16(ones, bp0, lpacc, 0, 0, 0);
      lpacc = __builtin_amdgcn_mfma_f32_16x16x32_bf16(ones, bp1, lpacc, 0, 0, 0);

      // PV: A = V^T frags (d-block x kv-half), B = bp
      const short8 av0l = *(const short8*)(Vs + rs);
      const short8 av1l = *(const short8*)(Vs + rs + 512);
      const short8 av2l = *(const short8*)(Vs + rs + 1024);
      const short8 av3l = *(const short8*)(Vs + rs + 1536);
      const short8 av0h = *(const short8*)(Vs + 2048 + rs);
      const short8 av1h = *(const short8*)(Vs + 2048 + rs + 512);
      const short8 av2h = *(const short8*)(Vs + 2048 + rs + 1024);
      const short8 av3h = *(const short8*)(Vs + 2048 + rs + 1536);
      oa0 = __builtin_amdgcn_mfma_f32_16x16x32_bf16(av0l, bp0, oa0, 0, 0, 0);
      oa1 = __builtin_amdgcn_mfma_f32_16x16x32_bf16(av1l, bp0, oa1, 0, 0, 0);
      oa2 = __builtin_amdgcn_mfma_f32_16x16x32_bf16(av2l, bp0, oa2, 0, 0, 0);
      oa3 = __builtin_amdgcn_mfma_f32_16x16x32_bf16(av3l, bp0, oa3, 0, 0, 0);
      oa0 = __builtin_amdgcn_mfma_f32_16x16x32_bf16(av0h, bp1, oa0, 0, 0, 0);
      oa1 = __builtin_amdgcn_mfma_f32_16x16x32_bf16(av1h, bp1, oa1, 0, 0, 0);
      oa2 = __builtin_amdgcn_mfma_f32_16x16x32_bf16(av2h, bp1, oa2, 0, 0, 0);
      oa3 = __builtin_amdgcn_mfma_f32_16x16x32_bf16(av3h, bp1, oa3, 0, 0, 0);
    }

    // lpacc[0] holds sum_kv P[q=l15] (all rows identical; k-reduction done
    // inside the MFMA, so no cross-quad shuffle needed)
    const float il = 1.f / lpacc[0];

    // O^T: lane holds q=l15's d = db*16 + 4*quad + r  -> 4x ushort4 stores
    unsigned short* ob = Qio + ((size_t)(b * SEQL + qrow)) * DMODEL + h * DHEAD + quad * 4;
    {
      ushort4 v;
      v.x = f2bf(oa0[0] * il); v.y = f2bf(oa0[1] * il);
      v.z = f2bf(oa0[2] * il); v.w = f2bf(oa0[3] * il);
      *(ushort4*)(ob) = v;
      v.x = f2bf(oa1[0] * il); v.y = f2bf(oa1[1] * il);
      v.z = f2bf(oa1[2] * il); v.w = f2bf(oa1[3] * il);
      *(ushort4*)(ob + 16) = v;
      v.x = f2bf(oa2[0] * il); v.y = f2bf(oa2[1] * il);
      v.z = f2bf(oa2[2] * il); v.w = f2bf(oa2[3] * il);
      *(ushort4*)(ob + 32) = v;
      v.x = f2bf(oa3[0] * il); v.y = f2bf(oa3[1] * il);
      v.z = f2bf(oa3[2] * il); v.w = f2bf(oa3[3] * il);
      *(ushort4*)(ob + 48) = v;
    }
  }
}

// ---------------------------------------------------------------------------
extern "C" void kernel_launch(void* const* d_in, const int* in_sizes, int n_in,
                              void* d_out, int out_size, void* d_ws, size_t ws_size,
                              hipStream_t stream) {
  (void)in_sizes; (void)n_in; (void)out_size; (void)ws_size;
  const float* x  = (const float*)d_in[0];
  const int* tpos = (const int*)d_in[1];
  const float* Wq = (const float*)d_in[2];
  const float* Wk = (const float*)d_in[3];
  const float* Wv = (const float*)d_in[4];
  const float* Wo = (const float*)d_in[5];
  float* out      = (float*)d_out;

  char* ws = (char*)d_ws;
  const size_t MB = 1024 * 1024;
  unsigned short* Qf  = (unsigned short*)(ws);            // 8 MB
  unsigned short* Kf  = (unsigned short*)(ws + 8 * MB);   // 8 MB
  unsigned short* Vt  = (unsigned short*)(ws + 16 * MB);  // 8 MB
  unsigned short* xb  = (unsigned short*)(ws + 24 * MB);  // 8 MB
  unsigned short* wqb = (unsigned short*)(ws + 32 * MB);  // 2 MB
  unsigned short* wkb = (unsigned short*)(ws + 34 * MB);  // 2 MB
  unsigned short* wvb = (unsigned short*)(ws + 36 * MB);  // 2 MB
  unsigned short* wob = (unsigned short*)(ws + 38 * MB);  // 2 MB
  float2* tbl         = (float2*)(ws + 40 * MB);          // 512 KB -> 40.5 MB

  // fp32 -> bf16 conversion (x + 4 weights) + RoPE cos/sin table (y==8)
  cvt_bf16<<<dim3(512, 9), 256, 0, stream>>>(x, Wq, Wk, Wv, Wo, tpos,
                                             xb, wqb, wkb, wvb, wob, tbl);
  // Q,K,V projections with FUSED RoPE (table slice staged in LDS);
  // V written transposed.
  gemm_qkv<<<dim3(8, 32, 3), 256, 0, stream>>>(xb, wqb, wkb, wvb, Qf, Kf, Vt,
                                               tbl, MROWS, DMODEL, DMODEL);
  // causal attention; 512 paired blocks (uniform 33 trips), XCD-swizzled
  attn_kernel<<<dim3(512), 256, 0, stream>>>(Kf, Vt, Qf);
  // output projection (bf16 A, bf16 W, fp32 out)
  gemm_out<<<dim3(8, 32, 1), 256, 0, stream>>>(Qf, wob, out, MROWS, DMODEL, DMODEL);
}

// Round 14
// 187.640 us; speedup vs baseline: 1.1107x; 1.0198x over previous
//
#include <hip/hip_runtime.h>
#include <cstdint>
#include <cstddef>

#define SEQL   2048
#define DMODEL 1024
#define NHEADS 16
#define DHEAD  64
#define MROWS  4096   // BATCH * SEQ

typedef __attribute__((ext_vector_type(8))) short short8;   // 8 bf16 (4 VGPRs)
typedef __attribute__((ext_vector_type(4))) float f32x4;    // MFMA 16x16 C/D
typedef __attribute__((ext_vector_type(4))) unsigned int u32x4;

__device__ __forceinline__ unsigned short f2bf(float x) {
  unsigned int u = __float_as_uint(x);
  u += 0x7fffu + ((u >> 16) & 1u);   // round-to-nearest-even
  return (unsigned short)(u >> 16);
}
__device__ __forceinline__ float bf2f(unsigned short u) {
  return __uint_as_float(((unsigned int)u) << 16);
}
// pack two f32 -> 2xbf16 in one VGPR (RNE, same rounding as f2bf)
__device__ __forceinline__ unsigned int cvtpk(float lo, float hi) {
  unsigned int r;
  asm("v_cvt_pk_bf16_f32 %0, %1, %2" : "=v"(r) : "v"(lo), "v"(hi));
  return r;
}
// load 8 contiguous fp32, round to 8 bf16
__device__ __forceinline__ short8 cvt8(const float* __restrict__ p) {
  const float4 lo = *(const float4*)p;
  const float4 hi = *(const float4*)(p + 4);
  short8 v;
  v[0] = (short)f2bf(lo.x); v[1] = (short)f2bf(lo.y);
  v[2] = (short)f2bf(lo.z); v[3] = (short)f2bf(lo.w);
  v[4] = (short)f2bf(hi.x); v[5] = (short)f2bf(hi.y);
  v[6] = (short)f2bf(hi.z); v[7] = (short)f2bf(hi.w);
  return v;
}
// async global->LDS, 16B per lane; lds base must be wave-uniform,
// GLOBAL SOURCE IS PER-LANE (lane l's 16B land at lds_base + l*16).
__device__ __forceinline__ void gload_lds16(const unsigned short* g, unsigned short* l) {
  __builtin_amdgcn_global_load_lds(
      (const __attribute__((address_space(1))) unsigned int*)g,
      (__attribute__((address_space(3))) unsigned int*)l, 16, 0, 0);
}

// ---------------------------------------------------------------------------
// One-shot fp32 -> bf16 conversion of x and the four weight matrices,
// PLUS the RoPE cos/sin table [2048 pos][32 i] float2 (512 KB, y==8 slice).
// ---------------------------------------------------------------------------
__global__ __launch_bounds__(256) void cvt_bf16(
    const float* __restrict__ x,  const float* __restrict__ wq,
    const float* __restrict__ wk, const float* __restrict__ wv,
    const float* __restrict__ wo, const int* __restrict__ pos_arr,
    unsigned short* __restrict__ xb,  unsigned short* __restrict__ wqb,
    unsigned short* __restrict__ wkb, unsigned short* __restrict__ wvb,
    unsigned short* __restrict__ wob, float2* __restrict__ tbl) {
  const int y = blockIdx.y;
  if (y == 8) {
    // RoPE table: id = s*32 + i
    const int id = blockIdx.x * 256 + threadIdx.x;
    if (id < SEQL * 32) {
      const int s = id >> 5, i = id & 31;
      const float pos = (float)pos_arr[s];
      // log2(10000)/32 = 0.4152410118609203
      const float inv = exp2f((float)i * -0.4152410118609203f);
      float ss, cc;
      sincosf(pos * inv, &ss, &cc);
      tbl[id] = make_float2(cc, ss);
    }
    return;
  }
  const float* src; unsigned short* dst;
  if (y < 4)       { src = x + ((size_t)y << 20); dst = xb + ((size_t)y << 20); }
  else if (y == 4) { src = wq; dst = wqb; }
  else if (y == 5) { src = wk; dst = wkb; }
  else if (y == 6) { src = wv; dst = wvb; }
  else             { src = wo; dst = wob; }
  const size_t i = ((size_t)blockIdx.x * 256 + threadIdx.x) * 8;
  *(short8*)(dst + i) = cvt8(src + i);
}

// ---------------------------------------------------------------------------
// QKV projection + R20 swizzle + R23 fused RoPE + R24 XCD-grouped grid.
// R23 rocprof: FETCH 38MB vs ~14.5 ideal — grid (8,32,3) dispatches the 8
// n-blocks sharing one 256KB A-tile onto 8 DIFFERENT XCDs (XCD ~ id%8), so
// every XCD re-fetches every A-tile.  R24: 1D grid, id = x*96 + z*32 + y
// -> id%8 = y%8 (96,32 === 0 mod 8): all 24 same-A blocks (8n x 3z) land on
// ONE XCD; per-XCD A set = 4 m-tiles = 1MB (L2-resident).  Bijective remap,
// no math change.  z=0 -> Q (pre-scaled 0.125); z=1 -> K; z=2 -> V^T.
// ---------------------------------------------------------------------------
__global__ __launch_bounds__(256) void gemm_qkv(
    const unsigned short* __restrict__ A,
    const unsigned short* __restrict__ W0, const unsigned short* __restrict__ W1,
    const unsigned short* __restrict__ W2,
    unsigned short* __restrict__ C0, unsigned short* __restrict__ C1,
    unsigned short* __restrict__ Vt, const float2* __restrict__ tbl,
    int Mda, int Nda, int Kda) {
  const int id = blockIdx.x;          // 0..767
  const int xn = id / 96;             // n-block 0..7
  const int w96 = id % 96;
  const int bz = w96 >> 5;            // weight select 0..2
  const int by = w96 & 31;            // m-block 0..31

  const unsigned short* W;
  if (bz == 0)      W = W0;
  else if (bz == 1) W = W1;
  else              W = W2;

  __shared__ __attribute__((aligned(16))) unsigned short As[128 * 32];
  __shared__ __attribute__((aligned(16))) unsigned short Bs[128 * 32];
  __shared__ __attribute__((aligned(16))) float2 Ts[128 * 32];   // 32 KB

  const int t = threadIdx.x;
  const int m0 = by * 128, n0 = xn * 128;
  const int w = t >> 6, lane = t & 63;
  const int l15 = lane & 15, quad = lane >> 4;
  const int wm = (w >> 1) * 64, wn = (w & 1) * 64;

  // pre-swizzled source: thread t (physical slot t / 256+t) loads logical
  // slot tx = t ^ ((t>>3)&7)  ->  row = tx>>2, col = (tx&3)*8
  const int tx = t ^ ((t >> 3) & 7);
  const int r1 = tx >> 2,      c1 = (tx & 3) * 8;
  const int r2 = 64 + r1,      c2 = c1;
  unsigned short* asd1 = As + (size_t)(w << 6) * 8;
  unsigned short* asd2 = As + (size_t)(256 + (w << 6)) * 8;
  unsigned short* bsd1 = Bs + (size_t)(w << 6) * 8;
  unsigned short* bsd2 = Bs + (size_t)(256 + (w << 6)) * 8;

  // stage this block's RoPE table slice (rows s0..s0+127, contiguous 32 KB)
  // into Ts; per-lane source offset (lane*16B) matches the hardware's
  // lane*16B LDS placement -> linear copy.
  if (bz != 2) {
    const int s0 = m0 & (SEQL - 1);
    const unsigned short* tsrc = (const unsigned short*)(tbl + (size_t)s0 * 32);
    unsigned short* tdst = (unsigned short*)Ts;
#pragma unroll
    for (int c = 0; c < 8; ++c) {
      const size_t seg = (size_t)(c * 4 + w) * 512;   // shorts (1 KB per wave-seg)
      gload_lds16(tsrc + seg + (size_t)lane * 8, tdst + seg);
    }
  }

  f32x4 acc[4][4] = {};

  for (int k0 = 0; k0 < Kda; k0 += 32) {
    __syncthreads();
    gload_lds16(A + (size_t)(m0 + r1) * Kda + k0 + c1, asd1);
    gload_lds16(A + (size_t)(m0 + r2) * Kda + k0 + c2, asd2);
    gload_lds16(W + (size_t)(n0 + r1) * Kda + k0 + c1, bsd1);
    gload_lds16(W + (size_t)(n0 + r2) * Kda + k0 + c2, bsd2);
    __syncthreads();

    short8 af[4], bfr[4];
#pragma unroll
    for (int i = 0; i < 4; ++i) {
      const int u = (wm + i * 16 + l15) * 4 + quad;
      const int p = u ^ ((u >> 3) & 7);
      af[i] = *(const short8*)(&As[p * 8]);
    }
#pragma unroll
    for (int j = 0; j < 4; ++j) {
      const int u = (wn + j * 16 + l15) * 4 + quad;
      const int p = u ^ ((u >> 3) & 7);
      bfr[j] = *(const short8*)(&Bs[p * 8]);
    }
#pragma unroll
    for (int i = 0; i < 4; ++i)
#pragma unroll
      for (int j = 0; j < 4; ++j)
        acc[i][j] = __builtin_amdgcn_mfma_f32_16x16x32_bf16(af[i], bfr[j], acc[i][j], 0, 0, 0);
  }

  if (bz != 2) {
    unsigned short* C = (bz == 0) ? C0 : C1;
    const float scale = (bz == 0) ? 0.125f : 1.0f;
    const int ii_base = (l15 >> 1);              // + j*8
    const bool even = (l15 & 1) == 0;
#pragma unroll
    for (int i = 0; i < 4; ++i)
#pragma unroll
      for (int j = 0; j < 4; ++j) {
        const int col = n0 + wn + j * 16 + l15;
        const int ii = j * 8 + ii_base;          // rope pair index (d>>1)
#pragma unroll
        for (int r = 0; r < 4; ++r) {
          const int lrow = wm + i * 16 + quad * 4 + r;
          const float v = acc[i][j][r];
          const float p = __shfl_xor(v, 1);      // partner lane = col^1
          const float e = even ? v : p;
          const float o = even ? p : v;
          const float2 cssn = Ts[lrow * 32 + ii];
          const float rot = even ? (e * cssn.x - o * cssn.y)
                                 : (e * cssn.y + o * cssn.x);
          C[(size_t)(m0 + lrow) * Nda + col] = f2bf(rot * scale);
        }
      }
  } else {
    // V transposed write: 4 consecutive s-values per 8B store
#pragma unroll
    for (int i = 0; i < 4; ++i) {
      const int srow = m0 + wm + i * 16 + quad * 4;   // b*SEQL + s (s%4==0)
      const int bq = srow >> 11, s = srow & (SEQL - 1);
#pragma unroll
      for (int j = 0; j < 4; ++j) {
        const int col = n0 + wn + j * 16 + l15;       // h*64 + d
        ushort4 v;
        v.x = f2bf(acc[i][j][0]); v.y = f2bf(acc[i][j][1]);
        v.z = f2bf(acc[i][j][2]); v.w = f2bf(acc[i][j][3]);
        *(ushort4*)(Vt + ((size_t)(bq * DMODEL + col)) * SEQL + s) = v;
      }
    }
  }
}

// ---------------------------------------------------------------------------
// Output projection: A bf16 [M][K], W bf16 [N][K], C fp32 [M][N]
// R20 swizzle + R24 XCD-grouped 1D grid (id = x*32 + y -> id%8 = y%8:
// the 8 n-blocks sharing an A m-tile land on one XCD).
// ---------------------------------------------------------------------------
__global__ __launch_bounds__(256) void gemm_out(
    const unsigned short* __restrict__ A,
    const unsigned short* __restrict__ W,
    float* __restrict__ C,
    int Mda, int Nda, int Kda) {
  __shared__ __attribute__((aligned(16))) unsigned short As[128 * 32];
  __shared__ __attribute__((aligned(16))) unsigned short Bs[128 * 32];

  const int id = blockIdx.x;          // 0..255
  const int xn = id >> 5;             // n-block 0..7
  const int by = id & 31;             // m-block 0..31

  const int t = threadIdx.x;
  const int m0 = by * 128, n0 = xn * 128;
  const int w = t >> 6, lane = t & 63;
  const int l15 = lane & 15, quad = lane >> 4;
  const int wm = (w >> 1) * 64, wn = (w & 1) * 64;

  const int tx = t ^ ((t >> 3) & 7);
  const int r1 = tx >> 2,      c1 = (tx & 3) * 8;
  const int r2 = 64 + r1,      c2 = c1;
  unsigned short* asd1 = As + (size_t)(w << 6) * 8;
  unsigned short* asd2 = As + (size_t)(256 + (w << 6)) * 8;
  unsigned short* bsd1 = Bs + (size_t)(w << 6) * 8;
  unsigned short* bsd2 = Bs + (size_t)(256 + (w << 6)) * 8;

  f32x4 acc[4][4] = {};

  for (int k0 = 0; k0 < Kda; k0 += 32) {
    __syncthreads();
    gload_lds16(A + (size_t)(m0 + r1) * Kda + k0 + c1, asd1);
    gload_lds16(A + (size_t)(m0 + r2) * Kda + k0 + c2, asd2);
    gload_lds16(W + (size_t)(n0 + r1) * Kda + k0 + c1, bsd1);
    gload_lds16(W + (size_t)(n0 + r2) * Kda + k0 + c2, bsd2);
    __syncthreads();

    short8 af[4], bfr[4];
#pragma unroll
    for (int i = 0; i < 4; ++i) {
      const int u = (wm + i * 16 + l15) * 4 + quad;
      const int p = u ^ ((u >> 3) & 7);
      af[i] = *(const short8*)(&As[p * 8]);
    }
#pragma unroll
    for (int j = 0; j < 4; ++j) {
      const int u = (wn + j * 16 + l15) * 4 + quad;
      const int p = u ^ ((u >> 3) & 7);
      bfr[j] = *(const short8*)(&Bs[p * 8]);
    }
#pragma unroll
    for (int i = 0; i < 4; ++i)
#pragma unroll
      for (int j = 0; j < 4; ++j)
        acc[i][j] = __builtin_amdgcn_mfma_f32_16x16x32_bf16(af[i], bfr[j], acc[i][j], 0, 0, 0);
  }

#pragma unroll
  for (int i = 0; i < 4; ++i)
#pragma unroll
    for (int j = 0; j < 4; ++j)
#pragma unroll
      for (int r = 0; r < 4; ++r) {
        int row = m0 + wm + i * 16 + quad * 4 + r;
        int col = n0 + wn + j * 16 + l15;
        C[(size_t)row * Nda + col] = acc[i][j][r];
      }
}

// ---------------------------------------------------------------------------
// Causal attention — R0 structure + R19 serial-chain VALU diet (cvtpk pack +
// lp row-sum in the matrix pipe).
// ---------------------------------------------------------------------------
__global__ __launch_bounds__(256, 2) void attn_kernel(const unsigned short* __restrict__ Kf,
                                                      const unsigned short* __restrict__ Vt,
                                                      unsigned short* __restrict__ Qio) {
  __shared__ __attribute__((aligned(16))) unsigned short Ks[4096];  // 8 KB: kv64 x d64
  __shared__ __attribute__((aligned(16))) unsigned short Vs[4096];  // 8 KB: d64 x kv64

  const int id = blockIdx.x;                    // id = grp*128 + qpair*8 + xcd
  const int bh = ((id >> 7) << 3) | (id & 7);   // grp*8 + xcd (L2 locality)
  const int qpair = (id >> 3) & 15;             // 0..15
  const int b = bh >> 4, h = bh & 15;
  const int w = threadIdx.x >> 6;
  const int lane = threadIdx.x & 63;
  const int l15 = lane & 15, quad = lane >> 4;

  // staging source addresses (lane-permuted so LDS slot = fragment layout)
  const int g = (w << 6) | lane;
  const int ktau = g >> 7, kseg = (g >> 4) & 7, km = g & 15;
  const int kvl = 8 * (km >> 2) + (km & 3) + 4 * ktau;
  const unsigned short* kstage = Kf + ((size_t)(b * SEQL + kvl)) * DMODEL + h * DHEAD + kseg * 8;
  const int vdb = (g >> 6) & 3, vq = (g >> 4) & 3, vm = g & 15;
  const unsigned short* vstage = Vt + ((size_t)(bh * DHEAD + vdb * 16 + vm)) * SEQL + vq * 8;
  unsigned short* kdst0 = Ks + (size_t)(w << 6) * 8;          // kv 0..31 half
  unsigned short* kdst1 = Ks + 2048 + (size_t)(w << 6) * 8;   // kv 32..63 half
  unsigned short* vdst0 = Vs + (size_t)(w << 6) * 8;
  unsigned short* vdst1 = Vs + 2048 + (size_t)(w << 6) * 8;

  // fragment read offset (shorts) within a 2048-short half
  const int rs = (l15 + (quad << 4)) << 3;

  // all-ones bf16 A-fragment for the lp row-sum MFMA
  const short8 ones = {(short)0x3F80, (short)0x3F80, (short)0x3F80, (short)0x3F80,
                       (short)0x3F80, (short)0x3F80, (short)0x3F80, (short)0x3F80};

#pragma unroll 1
  for (int phase = 0; phase < 2; ++phase) {
    const int qblk = (phase == 0) ? qpair : 31 - qpair;
    const int qw = qblk * 64 + w * 16;
    const int qrow = qw + l15;

    // Q B-frag: n=l15 (q), k=8*quad+j (d)
    const unsigned short* qp = Qio + ((size_t)(b * SEQL + qrow)) * DMODEL + h * DHEAD + quad * 8;
    const short8 bq0 = *(const short8*)(qp);
    const short8 bq1 = *(const short8*)(qp + 32);

    f32x4 oa0 = {0.f, 0.f, 0.f, 0.f}, oa1 = oa0, oa2 = oa0, oa3 = oa0;
    f32x4 lpacc = oa0;

    const int trips = qblk + 1;   // kv64 tiles; block-uniform
    for (int t = 0; t < trips; ++t) {
      const int kv0 = t * 64;
      __syncthreads();   // all waves done reading previous tile
      gload_lds16(kstage + (size_t)kv0 * DMODEL, kdst0);
      gload_lds16(kstage + (size_t)(kv0 + 32) * DMODEL, kdst1);
      gload_lds16(vstage + kv0, vdst0);
      gload_lds16(vstage + kv0 + 32, vdst1);
      __syncthreads();   // staged data visible

      // QK^T: 4 score accumulators (kv groups +0, +4, +32, +36)
      const short8 ak10 = *(const short8*)(Ks + rs);
      const short8 ak11 = *(const short8*)(Ks + rs + 512);
      const short8 ak20 = *(const short8*)(Ks + rs + 1024);
      const short8 ak21 = *(const short8*)(Ks + rs + 1536);
      const short8 ak30 = *(const short8*)(Ks + 2048 + rs);
      const short8 ak31 = *(const short8*)(Ks + 2048 + rs + 512);
      const short8 ak40 = *(const short8*)(Ks + 2048 + rs + 1024);
      const short8 ak41 = *(const short8*)(Ks + 2048 + rs + 1536);
      f32x4 z = {0.f, 0.f, 0.f, 0.f};
      f32x4 s1 = __builtin_amdgcn_mfma_f32_16x16x32_bf16(ak10, bq0, z, 0, 0, 0);
      s1 = __builtin_amdgcn_mfma_f32_16x16x32_bf16(ak11, bq1, s1, 0, 0, 0);
      f32x4 s2 = __builtin_amdgcn_mfma_f32_16x16x32_bf16(ak20, bq0, z, 0, 0, 0);
      s2 = __builtin_amdgcn_mfma_f32_16x16x32_bf16(ak21, bq1, s2, 0, 0, 0);
      f32x4 s3 = __builtin_amdgcn_mfma_f32_16x16x32_bf16(ak30, bq0, z, 0, 0, 0);
      s3 = __builtin_amdgcn_mfma_f32_16x16x32_bf16(ak31, bq1, s3, 0, 0, 0);
      f32x4 s4 = __builtin_amdgcn_mfma_f32_16x16x32_bf16(ak40, bq0, z, 0, 0, 0);
      s4 = __builtin_amdgcn_mfma_f32_16x16x32_bf16(ak41, bq1, s4, 0, 0, 0);

      // exp (+causal mask on the straddle trip) -> PV B-operands via cvtpk
      short8 bp0, bp1;
      if (kv0 + 63 <= qw) {   // wave-uniform fast path: no masking needed
        const float p10 = __expf(s1[0]), p11 = __expf(s1[1]);
        const float p12 = __expf(s1[2]), p13 = __expf(s1[3]);
        const float p20 = __expf(s2[0]), p21 = __expf(s2[1]);
        const float p22 = __expf(s2[2]), p23 = __expf(s2[3]);
        const float p30 = __expf(s3[0]), p31 = __expf(s3[1]);
        const float p32 = __expf(s3[2]), p33 = __expf(s3[3]);
        const float p40 = __expf(s4[0]), p41 = __expf(s4[1]);
        const float p42 = __expf(s4[2]), p43 = __expf(s4[3]);
        u32x4 lo, hi;
        lo[0] = cvtpk(p10, p11); lo[1] = cvtpk(p12, p13);
        lo[2] = cvtpk(p20, p21); lo[3] = cvtpk(p22, p23);
        hi[0] = cvtpk(p30, p31); hi[1] = cvtpk(p32, p33);
        hi[2] = cvtpk(p40, p41); hi[3] = cvtpk(p42, p43);
        bp0 = __builtin_bit_cast(short8, lo);
        bp1 = __builtin_bit_cast(short8, hi);
      } else {
        float p1[4], p2[4], p3[4], p4[4];
#pragma unroll
        for (int r = 0; r < 4; ++r) {
          const int kv1 = kv0 + 8 * quad + r;
          p1[r] = (kv1 > qrow)      ? 0.f : __expf(s1[r]);
          p2[r] = (kv1 + 4 > qrow)  ? 0.f : __expf(s2[r]);
          p3[r] = (kv1 + 32 > qrow) ? 0.f : __expf(s3[r]);
          p4[r] = (kv1 + 36 > qrow) ? 0.f : __expf(s4[r]);
        }
        u32x4 lo, hi;
        lo[0] = cvtpk(p1[0], p1[1]); lo[1] = cvtpk(p1[2], p1[3]);
        lo[2] = cvtpk(p2[0], p2[1]); lo[3] = cvtpk(p2[2], p2[3]);
        hi[0] = cvtpk(p3[0], p3[1]); hi[1] = cvtpk(p3[2], p3[3]);
        hi[2] = cvtpk(p4[0], p4[1]); hi[3] = cvtpk(p4[2], p4[3]);
        bp0 = __builtin_bit_cast(short8, lo);
        bp1 = __builtin_bit_cast(short8, hi);
      }

      // lp row-sum in the matrix pipe: D[row,q] = sum_k 1 * P[k,q]
      lpacc = __builtin_amdgcn_mfma_f32_16x16x32_bf16(ones, bp0, lpacc, 0, 0, 0);
      lpacc = __builtin_amdgcn_mfma_f32_16x16x32_bf16(ones, bp1, lpacc, 0, 0, 0);

      // PV: A = V^T frags (d-block x kv-half), B = bp
      const short8 av0l = *(const short8*)(Vs + rs);
      const short8 av1l = *(const short8*)(Vs + rs + 512);
      const short8 av2l = *(const short8*)(Vs + rs + 1024);
      const short8 av3l = *(const short8*)(Vs + rs + 1536);
      const short8 av0h = *(const short8*)(Vs + 2048 + rs);
      const short8 av1h = *(const short8*)(Vs + 2048 + rs + 512);
      const short8 av2h = *(const short8*)(Vs + 2048 + rs + 1024);
      const short8 av3h = *(const short8*)(Vs + 2048 + rs + 1536);
      oa0 = __builtin_amdgcn_mfma_f32_16x16x32_bf16(av0l, bp0, oa0, 0, 0, 0);
      oa1 = __builtin_amdgcn_mfma_f32_16x16x32_bf16(av1l, bp0, oa1, 0, 0, 0);
      oa2 = __builtin_amdgcn_mfma_f32_16x16x32_bf16(av2l, bp0, oa2, 0, 0, 0);
      oa3 = __builtin_amdgcn_mfma_f32_16x16x32_bf16(av3l, bp0, oa3, 0, 0, 0);
      oa0 = __builtin_amdgcn_mfma_f32_16x16x32_bf16(av0h, bp1, oa0, 0, 0, 0);
      oa1 = __builtin_amdgcn_mfma_f32_16x16x32_bf16(av1h, bp1, oa1, 0, 0, 0);
      oa2 = __builtin_amdgcn_mfma_f32_16x16x32_bf16(av2h, bp1, oa2, 0, 0, 0);
      oa3 = __builtin_amdgcn_mfma_f32_16x16x32_bf16(av3h, bp1, oa3, 0, 0, 0);
    }

    // lpacc[0] holds sum_kv P[q=l15] (all rows identical; k-reduction done
    // inside the MFMA, so no cross-quad shuffle needed)
    const float il = 1.f / lpacc[0];

    // O^T: lane holds q=l15's d = db*16 + 4*quad + r  -> 4x ushort4 stores
    unsigned short* ob = Qio + ((size_t)(b * SEQL + qrow)) * DMODEL + h * DHEAD + quad * 4;
    {
      ushort4 v;
      v.x = f2bf(oa0[0] * il); v.y = f2bf(oa0[1] * il);
      v.z = f2bf(oa0[2] * il); v.w = f2bf(oa0[3] * il);
      *(ushort4*)(ob) = v;
      v.x = f2bf(oa1[0] * il); v.y = f2bf(oa1[1] * il);
      v.z = f2bf(oa1[2] * il); v.w = f2bf(oa1[3] * il);
      *(ushort4*)(ob + 16) = v;
      v.x = f2bf(oa2[0] * il); v.y = f2bf(oa2[1] * il);
      v.z = f2bf(oa2[2] * il); v.w = f2bf(oa2[3] * il);
      *(ushort4*)(ob + 32) = v;
      v.x = f2bf(oa3[0] * il); v.y = f2bf(oa3[1] * il);
      v.z = f2bf(oa3[2] * il); v.w = f2bf(oa3[3] * il);
      *(ushort4*)(ob + 48) = v;
    }
  }
}

// ---------------------------------------------------------------------------
extern "C" void kernel_launch(void* const* d_in, const int* in_sizes, int n_in,
                              void* d_out, int out_size, void* d_ws, size_t ws_size,
                              hipStream_t stream) {
  (void)in_sizes; (void)n_in; (void)out_size; (void)ws_size;
  const float* x  = (const float*)d_in[0];
  const int* tpos = (const int*)d_in[1];
  const float* Wq = (const float*)d_in[2];
  const float* Wk = (const float*)d_in[3];
  const float* Wv = (const float*)d_in[4];
  const float* Wo = (const float*)d_in[5];
  float* out      = (float*)d_out;

  char* ws = (char*)d_ws;
  const size_t MB = 1024 * 1024;
  unsigned short* Qf  = (unsigned short*)(ws);            // 8 MB
  unsigned short* Kf  = (unsigned short*)(ws + 8 * MB);   // 8 MB
  unsigned short* Vt  = (unsigned short*)(ws + 16 * MB);  // 8 MB
  unsigned short* xb  = (unsigned short*)(ws + 24 * MB);  // 8 MB
  unsigned short* wqb = (unsigned short*)(ws + 32 * MB);  // 2 MB
  unsigned short* wkb = (unsigned short*)(ws + 34 * MB);  // 2 MB
  unsigned short* wvb = (unsigned short*)(ws + 36 * MB);  // 2 MB
  unsigned short* wob = (unsigned short*)(ws + 38 * MB);  // 2 MB
  float2* tbl         = (float2*)(ws + 40 * MB);          // 512 KB -> 40.5 MB

  // fp32 -> bf16 conversion (x + 4 weights) + RoPE cos/sin table (y==8)
  cvt_bf16<<<dim3(512, 9), 256, 0, stream>>>(x, Wq, Wk, Wv, Wo, tpos,
                                             xb, wqb, wkb, wvb, wob, tbl);
  // Q,K,V projections with FUSED RoPE; 1D XCD-grouped grid (768 blocks)
  gemm_qkv<<<dim3(768), 256, 0, stream>>>(xb, wqb, wkb, wvb, Qf, Kf, Vt,
                                          tbl, MROWS, DMODEL, DMODEL);
  // causal attention; 512 paired blocks (uniform 33 trips), XCD-swizzled
  attn_kernel<<<dim3(512), 256, 0, stream>>>(Kf, Vt, Qf);
  // output projection; 1D XCD-grouped grid (256 blocks)
  gemm_out<<<dim3(256), 256, 0, stream>>>(Qf, wob, out, MROWS, DMODEL, DMODEL);
}